// Round 17
// baseline (651.059 us; speedup 1.0000x reference)
//
#include <hip/hip_runtime.h>
#include <hip/hip_fp16.h>

#define BSZ  5
#define PROJ 1000
#define DET  513
#define IMG  362
#define NPIX (IMG * IMG)          // 131044
#define SINO (PROJ * DET)         // 513000
#define NNZ  20000000

#define NSHARD     4
#define SHARD_COLS (SINO / NSHARD)   // 128250
#define RB_SHIFT   10
#define RB_PX      1024
#define NRBIN      128
#define NBIN       (NRBIN * NSHARD)  // 512

#define SCAT_BLOCKS  256
#define CHUNK        78128           // ceil(NNZ/256) rounded to mult of 16
#define SCT_THREADS  1024

#define CAP        200               // slots per (bin,block) cell
#define CELLS_PER_BIN (SCAT_BLOCKS * CAP)   // 51200 slots per bin
#define OVF_CAP    65536

#define ACC_THREADS  512

// fixed-point: scale 2^14, bias 2^18, n-tag 2^24 in slot-3 high
#define FXSCALE 16384.0f
#define FXINV   (1.0f / 16384.0f)
#define FXB     262144               // 2^18
#define NTAG    0x1000000u           // 2^24

typedef int      i32x4 __attribute__((ext_vector_type(4)));
typedef float    f32x4 __attribute__((ext_vector_type(4)));
typedef unsigned u32x4 __attribute__((ext_vector_type(4)));

// no-return LDS atomics (fire-and-forget).
__device__ __forceinline__ unsigned lds_off(const void* p) {
    return (unsigned)(size_t)p;
}
__device__ __forceinline__ void ds_add_u64_nr(unsigned off, unsigned long long v) {
    asm volatile("ds_add_u64 %0, %1" :: "v"(off), "v"(v) : "memory");
}
// per-wave drain: inline-asm DS ops COMPLETE before the following barrier.
__device__ __forceinline__ void lgkm_drain() {
    asm volatile("s_waitcnt lgkmcnt(0)" ::: "memory");
}

__device__ __forceinline__ int bin_of(int row, int col) {
    return ((row >> RB_SHIFT) << 2) | (col / SHARD_COLS);
}

// ---------------- fast path kernels ----------------

// single pass: sino bf16 prologue + direct claim-and-store into [bin][blk] cells.
// No tile sort: L2 write-combines the per-block 512 append streams (2 MB/XCD).
__global__ __launch_bounds__(SCT_THREADS) void k_scatter(
        const float* __restrict__ sino, u32x4* __restrict__ sino_b,
        const float* __restrict__ vals, const int* __restrict__ rows,
        const int* __restrict__ cols,
        unsigned* __restrict__ recA, unsigned short* __restrict__ recB,
        unsigned* __restrict__ gcnt,
        unsigned long long* __restrict__ ovf, unsigned* __restrict__ ovf_n) {
    __shared__ unsigned cnt[NBIN];   // 2 KB — whole-chunk running claims
    const int t = threadIdx.x;

    // ---- sino -> bf16 packed table prologue (2 cols/thread); only accum reads it
    {
        const int cbase = blockIdx.x * (SCT_THREADS * 2) + t * 2;
#pragma unroll
        for (int k = 0; k < 2; ++k) {
            const int c = cbase + k;
            if (c < SINO) {
                unsigned b[5];
#pragma unroll
                for (int j = 0; j < 5; ++j) {
                    const unsigned u = __float_as_uint(sino[(size_t)j * SINO + c]);
                    b[j] = (u + 0x7FFFu + ((u >> 16) & 1u)) >> 16;   // RNE to bf16
                }
                u32x4 o;
                o.x = b[0] | (b[1] << 16);
                o.y = b[2] | (b[3] << 16);
                o.z = b[4];
                o.w = 0u;
                sino_b[c] = o;
            }
        }
    }

    if (t < NBIN) cnt[t] = 0u;
    __syncthreads();

    const int lo = blockIdx.x * CHUNK;
    const int hi = (lo + CHUNK < NNZ) ? lo + CHUNK : NNZ;
    const unsigned blkoff = (unsigned)blockIdx.x * CAP;

    for (int i4 = lo / 4 + t; i4 * 4 < hi; i4 += SCT_THREADS) {
        const i32x4 r = __builtin_nontemporal_load(((const i32x4*)rows) + i4);
        const i32x4 q = __builtin_nontemporal_load(((const i32x4*)cols) + i4);
        const f32x4 v = __builtin_nontemporal_load(((const f32x4*)vals) + i4);
#pragma unroll
        for (int k = 0; k < 4; ++k) {
            const int rr = r[k];
            const int qq = q[k];
            const float vf = v[k];
            const unsigned bn = (unsigned)bin_of(rr, qq);
            const unsigned pk = ((unsigned)(rr & (RB_PX - 1)) << 19) | (unsigned)qq;
            const unsigned vh = (unsigned)__half_as_ushort(__float2half(vf));
            const unsigned slot = atomicAdd(&cnt[bn], 1u);
            if (slot < CAP) {
                const unsigned pos = bn * (SCAT_BLOCKS * CAP) + blkoff + slot;
                recA[pos] = pk;
                recB[pos] = (unsigned short)vh;
            } else {
                const unsigned g = atomicAdd(ovf_n, 1u);
                if (g < OVF_CAP)
                    ovf[g] = ((unsigned long long)bn << 55)
                           | ((unsigned long long)pk << 26)
                           | (unsigned long long)vh;
            }
        }
    }
    __syncthreads();

    // write per-cell counts (capped) for accum: gcnt[blk][bin]
    if (t < NBIN) {
        const unsigned total = cnt[t];
        gcnt[(size_t)blockIdx.x * NBIN + t] = (total < CAP) ? total : CAP;
    }
}

// accumulate one bin from its contiguous [bin][blk] cell region (flat masked scan)
// per pixel: 3 u64: #1={q1 : q0+B} #2={q3 : q2+B} #3={q5+NTAG : q4+B}
__global__ __launch_bounds__(ACC_THREADS) void k_accum(
        const unsigned* __restrict__ recA, const unsigned short* __restrict__ recB,
        const unsigned* __restrict__ gcnt, const u32x4* __restrict__ sino_b,
        const unsigned long long* __restrict__ ovf, const unsigned* __restrict__ ovf_n,
        float* __restrict__ acc) {
    __shared__ unsigned long long l8[RB_PX * 3];   // 24 KB
    __shared__ unsigned fcnt[SCAT_BLOCKS];         //  1 KB
    const int t = threadIdx.x;
    const int bin = blockIdx.x;
    for (int j = t; j < RB_PX * 3; j += ACC_THREADS) l8[j] = 0ull;
    if (t < SCAT_BLOCKS) fcnt[t] = gcnt[(size_t)t * NBIN + bin];
    __syncthreads();

    const unsigned binbase = (unsigned)bin * CELLS_PER_BIN;
    for (unsigned i = (unsigned)t; i < CELLS_PER_BIN; i += ACC_THREADS) {
        const unsigned frag = i / CAP;             // magic-mul divide by 200
        const unsigned slot = i - frag * CAP;
        const unsigned a = recA[binbase + i];      // coalesced sequential
        const unsigned short hraw = recB[binbase + i];
        if (slot < fcnt[frag]) {
            const float v = __half2float(__ushort_as_half(hraw));
            const int col = (int)(a & 0x7FFFFu);
            const int lr  = (int)(a >> 19);
            const u32x4 sv = sino_b[col];
            const int q0 = __float2int_rn(v * __uint_as_float(sv.x << 16)         * FXSCALE);
            const int q1 = __float2int_rn(v * __uint_as_float(sv.x & 0xFFFF0000u) * FXSCALE);
            const int q2 = __float2int_rn(v * __uint_as_float(sv.y << 16)         * FXSCALE);
            const int q3 = __float2int_rn(v * __uint_as_float(sv.y & 0xFFFF0000u) * FXSCALE);
            const int q4 = __float2int_rn(v * __uint_as_float(sv.z << 16)         * FXSCALE);
            const int q5 = __float2int_rn(v * FXSCALE);
            const unsigned b = lds_off(&l8[(unsigned)lr * 3u]);
            ds_add_u64_nr(b,
                ((unsigned long long)(unsigned)q1 << 32) | (unsigned)(q0 + FXB));
            ds_add_u64_nr(b + 8,
                ((unsigned long long)(unsigned)q3 << 32) | (unsigned)(q2 + FXB));
            ds_add_u64_nr(b + 16,
                ((unsigned long long)((unsigned)q5 + NTAG) << 32) | (unsigned)(q4 + FXB));
        }
    }

    // fold in rare overflow records for this bin (same fixed-point path)
    {
        unsigned n = *ovf_n;
        if (n > OVF_CAP) n = OVF_CAP;
        for (unsigned i = (unsigned)t; i < n; i += ACC_THREADS) {
            const unsigned long long u = ovf[i];
            if ((unsigned)(u >> 55) != (unsigned)bin) continue;
            const float v = __half2float(__ushort_as_half((unsigned short)(u & 0xFFFFu)));
            const unsigned pk = (unsigned)((u >> 26) & 0x1FFFFFFFu);
            const int col = (int)(pk & 0x7FFFFu);
            const int lr  = (int)(pk >> 19);
            const u32x4 sv = sino_b[col];
            const int q0 = __float2int_rn(v * __uint_as_float(sv.x << 16)         * FXSCALE);
            const int q1 = __float2int_rn(v * __uint_as_float(sv.x & 0xFFFF0000u) * FXSCALE);
            const int q2 = __float2int_rn(v * __uint_as_float(sv.y << 16)         * FXSCALE);
            const int q3 = __float2int_rn(v * __uint_as_float(sv.y & 0xFFFF0000u) * FXSCALE);
            const int q4 = __float2int_rn(v * __uint_as_float(sv.z << 16)         * FXSCALE);
            const int q5 = __float2int_rn(v * FXSCALE);
            const unsigned b = lds_off(&l8[(unsigned)lr * 3u]);
            ds_add_u64_nr(b,
                ((unsigned long long)(unsigned)q1 << 32) | (unsigned)(q0 + FXB));
            ds_add_u64_nr(b + 8,
                ((unsigned long long)(unsigned)q3 << 32) | (unsigned)(q2 + FXB));
            ds_add_u64_nr(b + 16,
                ((unsigned long long)((unsigned)q5 + NTAG) << 32) | (unsigned)(q4 + FXB));
        }
    }
    lgkm_drain();
    __syncthreads();

    float* dst = acc + (size_t)bin * (RB_PX * 6);
    for (int px = t; px < RB_PX; px += ACC_THREADS) {
        const unsigned long long a0 = l8[px * 3 + 0];
        const unsigned long long a1 = l8[px * 3 + 1];
        const unsigned long long a2 = l8[px * 3 + 2];
        const unsigned hi3 = (unsigned)(a2 >> 32);
        const unsigned n = hi3 >> 24;                     // record count
        const long long nb = (long long)n * FXB;
        float* d = dst + px * 6;
        d[0] = (float)((long long)(unsigned)(a0 & 0xFFFFFFFFull) - nb) * FXINV;
        d[1] = (float)((int)(a0 >> 32)) * FXINV;
        d[2] = (float)((long long)(unsigned)(a1 & 0xFFFFFFFFull) - nb) * FXINV;
        d[3] = (float)((int)(a1 >> 32)) * FXINV;
        d[4] = (float)((long long)(unsigned)(a2 & 0xFFFFFFFFull) - nb) * FXINV;
        d[5] = (float)(hi3 & 0xFFFFFFu) * FXINV;          // sum of vals (positive)
    }
}

// sum 4 shards per pixel, divide, write [BSZ][NPIX]
__global__ void k_reduce(const float* __restrict__ acc, float* __restrict__ out) {
    const int p = blockIdx.x * blockDim.x + threadIdx.x;
    if (p < NPIX) {
        const int rbin = p >> RB_SHIFT, lr = p & (RB_PX - 1);
        float n0 = 0.f, n1 = 0.f, n2 = 0.f, n3 = 0.f, n4 = 0.f, den = 0.f;
#pragma unroll
        for (int s = 0; s < NSHARD; ++s) {
            const float* b = acc + ((size_t)(rbin * NSHARD + s) * RB_PX + lr) * 6;
            n0 += b[0]; n1 += b[1]; n2 += b[2];
            n3 += b[3]; n4 += b[4]; den += b[5];
        }
        const float inv = 1.f / den;
        out[0 * (size_t)NPIX + p] = n0 * inv;
        out[1 * (size_t)NPIX + p] = n1 * inv;
        out[2 * (size_t)NPIX + p] = n2 * inv;
        out[3 * (size_t)NPIX + p] = n3 * inv;
        out[4 * (size_t)NPIX + p] = n4 * inv;
    }
}

// ---------------- fallback kernels (small workspace) ----------------

__global__ void bp_scatter_fb_kernel(const float* __restrict__ sino,
                                     const float* __restrict__ vals,
                                     const int*   __restrict__ rows,
                                     const int*   __restrict__ cols,
                                     float* __restrict__ acc) {
    const long long stride = (long long)gridDim.x * blockDim.x;
    for (long long i = (long long)blockIdx.x * blockDim.x + threadIdx.x;
         i < NNZ; i += stride) {
        const float v = vals[i];
        const int   r = rows[i];
        const int   c = cols[i];
        atomicAdd(acc + (size_t)BSZ * NPIX + r, v);
#pragma unroll
        for (int b = 0; b < BSZ; ++b)
            atomicAdd(acc + (size_t)b * NPIX + r, v * sino[(size_t)b * SINO + c]);
    }
}

__global__ void bp_divide_fb_kernel(const float* __restrict__ acc,
                                    float* __restrict__ out) {
    const int i = blockIdx.x * blockDim.x + threadIdx.x;
    if (i < BSZ * NPIX) {
        const int p = i % NPIX;
        out[i] = acc[i] / acc[(size_t)BSZ * NPIX + p];
    }
}

// ---------------- launch ----------------

extern "C" void kernel_launch(void* const* d_in, const int* in_sizes, int n_in,
                              void* d_out, int out_size, void* d_ws, size_t ws_size,
                              hipStream_t stream) {
    const float* sino = (const float*)d_in[0];
    const float* vals = (const float*)d_in[1];
    const int*   rows = (const int*)d_in[2];
    const int*   cols = (const int*)d_in[3];
    float* out = (float*)d_out;

    // workspace layout (bytes, all 16B-aligned):
    //   recA   : 512 bins * 51200 * 4     = 104,857,600
    //   recB   : 512 bins * 51200 * 2     =  52,428,800
    //   sino_b : SINO * 16                =   8,208,000
    //   acc    : NBIN * RB_PX * 6 * 4     =  12,582,912
    //   gcnt   : SCAT_BLOCKS * NBIN * 4   =     524,288
    //   ovf    : OVF_CAP * 8              =     524,288
    //   ovf_n  : 16
    //   total ~ 179.1 MB
    const size_t recA_b   = (size_t)NBIN * CELLS_PER_BIN * 4;
    const size_t recB_b   = (size_t)NBIN * CELLS_PER_BIN * 2;
    const size_t sino_b_b = (size_t)SINO * 16;
    const size_t acc_b    = (size_t)NBIN * RB_PX * 6 * 4;
    const size_t gcnt_b   = (size_t)SCAT_BLOCKS * NBIN * 4;
    const size_t ovf_b    = (size_t)OVF_CAP * 8;
    const size_t need = recA_b + recB_b + sino_b_b + acc_b + gcnt_b + ovf_b + 16;

    if (ws_size >= need) {
        char* w = (char*)d_ws;
        unsigned*       recA = (unsigned*)w;                w += recA_b;
        unsigned short* recB = (unsigned short*)w;          w += recB_b;
        u32x4*    sinob  = (u32x4*)w;                       w += sino_b_b;
        float*    acc    = (float*)w;                       w += acc_b;
        unsigned* gcnt   = (unsigned*)w;                    w += gcnt_b;
        unsigned long long* ovf = (unsigned long long*)w;   w += ovf_b;
        unsigned* ovf_n  = (unsigned*)w;

        (void)hipMemsetAsync(ovf_n, 0, 4, stream);
        k_scatter<<<SCAT_BLOCKS, SCT_THREADS, 0, stream>>>(
            sino, sinob, vals, rows, cols, recA, recB, gcnt, ovf, ovf_n);
        k_accum<<<NBIN, ACC_THREADS, 0, stream>>>(
            recA, recB, gcnt, sinob, ovf, ovf_n, acc);
        k_reduce<<<(NPIX + 255) / 256, 256, 0, stream>>>(acc, out);
    } else {
        float* acc = (float*)d_ws;
        (void)hipMemsetAsync(acc, 0, (size_t)(BSZ + 1) * NPIX * sizeof(float), stream);
        bp_scatter_fb_kernel<<<2048, 256, 0, stream>>>(sino, vals, rows, cols, acc);
        bp_divide_fb_kernel<<<(BSZ * NPIX + 255) / 256, 256, 0, stream>>>(acc, out);
    }
}

// Round 18
// 222.704 us; speedup vs baseline: 2.9234x; 2.9234x over previous
//
#include <hip/hip_runtime.h>
#include <hip/hip_fp16.h>

#define BSZ  5
#define PROJ 1000
#define DET  513
#define IMG  362
#define NPIX (IMG * IMG)          // 131044
#define SINO (PROJ * DET)         // 513000
#define NNZ  20000000

#define NSHARD     4
#define SHARD_COLS (SINO / NSHARD)   // 128250
#define RB_SHIFT   10
#define RB_PX      1024
#define NRBIN      128
#define NBIN       (NRBIN * NSHARD)  // 512

#define SCAT_BLOCKS  256
#define CHUNK        78128           // ceil(NNZ/256) rounded to mult of 16
#define TILE         8192
#define SCT_THREADS  1024

#define CAP        192               // slots per (bin,block) cell; 768B/384B = whole lines
#define CELLS_PER_BIN (SCAT_BLOCKS * CAP)   // 49152 slots per bin
#define OVF_CAP    65536

#define ACC_THREADS  512

// 2-u64 fixed-point packing (per pixel):
//   u64#1: [62:42]=q2+B | [41:21]=q1+B | [20:0]=q0+B      (21-bit fields)
//   u64#2: [63:42]=(n<<14 | qden)      | [41:21]=q4+B | [20:0]=q3+B
// q_k = round(v*s_k * 2^10), |q|<=~5.6K, B=2^13; qden = round(v*2^7) <= 128
#define FXS   1024.0f
#define FXSI  (1.0f / 1024.0f)
#define DENS  128.0f
#define DENSI (1.0f / 128.0f)
#define B21   8192
#define M21   0x1FFFFFu

typedef int      i32x4 __attribute__((ext_vector_type(4)));
typedef float    f32x4 __attribute__((ext_vector_type(4)));
typedef unsigned u32x4 __attribute__((ext_vector_type(4)));

// no-return LDS atomics (fire-and-forget).
__device__ __forceinline__ unsigned lds_off(const void* p) {
    return (unsigned)(size_t)p;
}
__device__ __forceinline__ void ds_add_u64_nr(unsigned off, unsigned long long v) {
    asm volatile("ds_add_u64 %0, %1" :: "v"(off), "v"(v) : "memory");
}
// per-wave drain: inline-asm DS ops COMPLETE before the following barrier.
__device__ __forceinline__ void lgkm_drain() {
    asm volatile("s_waitcnt lgkmcnt(0)" ::: "memory");
}

__device__ __forceinline__ int bin_of(int row, int col) {
    return ((row >> RB_SHIFT) << 2) | (col / SHARD_COLS);
}

// build the two packed addends for one record and issue 2 no-rtn LDS adds
__device__ __forceinline__ void fx_accum(unsigned lds_base, float v, u32x4 sv) {
    const int q0 = __float2int_rn(v * __uint_as_float(sv.x << 16)         * FXS);
    const int q1 = __float2int_rn(v * __uint_as_float(sv.x & 0xFFFF0000u) * FXS);
    const int q2 = __float2int_rn(v * __uint_as_float(sv.y << 16)         * FXS);
    const int q3 = __float2int_rn(v * __uint_as_float(sv.y & 0xFFFF0000u) * FXS);
    const int q4 = __float2int_rn(v * __uint_as_float(sv.z << 16)         * FXS);
    const unsigned qd = (unsigned)__float2int_rn(v * DENS);   // <= 128
    const unsigned long long A0 =
          ((unsigned long long)(unsigned)(q2 + B21) << 42)
        | ((unsigned long long)(unsigned)(q1 + B21) << 21)
        |  (unsigned long long)(unsigned)(q0 + B21);
    const unsigned long long A1 =
          ((unsigned long long)((1u << 14) + qd) << 42)
        | ((unsigned long long)(unsigned)(q4 + B21) << 21)
        |  (unsigned long long)(unsigned)(q3 + B21);
    ds_add_u64_nr(lds_base, A0);
    ds_add_u64_nr(lds_base + 8, A1);
}

// ---------------- fast path kernels ----------------

// single pass: sino bf16 prologue + tile-local counting sort into [bin][blk] cells
// LDS record: [63:55]=bin(9) [54:45]=lr(10) [44:26]=col(19) [15:0]=fp16 val
__global__ __launch_bounds__(SCT_THREADS) void k_scatter(
        const float* __restrict__ sino, u32x4* __restrict__ sino_b,
        const float* __restrict__ vals, const int* __restrict__ rows,
        const int* __restrict__ cols,
        unsigned* __restrict__ recA, unsigned short* __restrict__ recB,
        unsigned* __restrict__ gcnt,
        unsigned long long* __restrict__ ovf, unsigned* __restrict__ ovf_n) {
    __shared__ unsigned cnt[NBIN];
    __shared__ unsigned toff[NBIN];
    __shared__ unsigned ebase[NBIN];
    __shared__ unsigned bs2[NBIN];
    __shared__ unsigned wsum[8];
    __shared__ unsigned long long sdata[TILE];   // 64 KB
    const int t = threadIdx.x;
    const int lane = t & 63;

    // ---- sino -> bf16 packed table prologue (2 cols/thread); only accum reads it
    {
        const int cbase = blockIdx.x * (SCT_THREADS * 2) + t * 2;
#pragma unroll
        for (int k = 0; k < 2; ++k) {
            const int c = cbase + k;
            if (c < SINO) {
                unsigned b[5];
#pragma unroll
                for (int j = 0; j < 5; ++j) {
                    const unsigned u = __float_as_uint(sino[(size_t)j * SINO + c]);
                    b[j] = (u + 0x7FFFu + ((u >> 16) & 1u)) >> 16;   // RNE to bf16
                }
                u32x4 o;
                o.x = b[0] | (b[1] << 16);
                o.y = b[2] | (b[3] << 16);
                o.z = b[4];
                o.w = 0u;
                sino_b[c] = o;
            }
        }
    }

    const int lo = blockIdx.x * CHUNK;
    const int hi = (lo + CHUNK < NNZ) ? lo + CHUNK : NNZ;
    if (lo >= hi) return;

    if (t < NBIN) {
        // transposed cell base: cell (bin, blk) at (bin*SCAT_BLOCKS + blk)*CAP
        bs2[t] = ((unsigned)t * SCAT_BLOCKS + (unsigned)blockIdx.x) * CAP;
        cnt[t] = 0u;
    }

    // stage tile 0 (8 records/thread)
    i32x4 sr0, sr1, sq0, sq1; f32x4 sv0, sv1;
    {
        const int n0 = (lo + TILE < hi) ? TILE : (hi - lo);
        if (t * 8 < n0) {
            const int i4 = (lo + t * 8) >> 2;
            sr0 = __builtin_nontemporal_load(((const i32x4*)rows) + i4);
            sr1 = __builtin_nontemporal_load(((const i32x4*)rows) + i4 + 1);
            sq0 = __builtin_nontemporal_load(((const i32x4*)cols) + i4);
            sq1 = __builtin_nontemporal_load(((const i32x4*)cols) + i4 + 1);
            sv0 = __builtin_nontemporal_load(((const f32x4*)vals) + i4);
            sv1 = __builtin_nontemporal_load(((const f32x4*)vals) + i4 + 1);
        }
    }
    __syncthreads();

    for (int tb = lo; tb < hi; tb += TILE) {
        const int n = (tb + TILE < hi) ? TILE : (hi - tb);   // mult of 16
        const bool act = (t * 8) < n;

        const i32x4 cr0 = sr0, cr1 = sr1, cq0 = sq0, cq1 = sq1;
        const f32x4 cv0 = sv0, cv1 = sv1;

        // issue next-tile staging loads (overlap with this tile's phases)
        const int ntb = tb + TILE;
        if (ntb < hi) {
            const int nn = (ntb + TILE < hi) ? TILE : (hi - ntb);
            if (t * 8 < nn) {
                const int i4 = (ntb + t * 8) >> 2;
                sr0 = __builtin_nontemporal_load(((const i32x4*)rows) + i4);
                sr1 = __builtin_nontemporal_load(((const i32x4*)rows) + i4 + 1);
                sq0 = __builtin_nontemporal_load(((const i32x4*)cols) + i4);
                sq1 = __builtin_nontemporal_load(((const i32x4*)cols) + i4 + 1);
                sv0 = __builtin_nontemporal_load(((const f32x4*)vals) + i4);
                sv1 = __builtin_nontemporal_load(((const f32x4*)vals) + i4 + 1);
            }
        }

        // Phase B: claim slots (8 tracked rtn atomics), build packed records
        unsigned long long r8[8];
        unsigned sl[8];
        if (act) {
#pragma unroll
            for (int k = 0; k < 8; ++k) {
                const int rr = (k < 4) ? cr0[k] : cr1[k - 4];
                const int qq = (k < 4) ? cq0[k] : cq1[k - 4];
                const float vf = (k < 4) ? cv0[k] : cv1[k - 4];
                const unsigned bn = (unsigned)bin_of(rr, qq);
                const unsigned vh = (unsigned)__half_as_ushort(__float2half(vf));
                r8[k] = ((unsigned long long)bn << 55)
                      | ((unsigned long long)(unsigned)(rr & (RB_PX - 1)) << 45)
                      | ((unsigned long long)(unsigned)qq << 26)
                      | (unsigned long long)vh;
                sl[k] = atomicAdd(&cnt[bn], 1u);
            }
        }
        __syncthreads();

        // Phase C: exclusive scan of cnt[512] via per-wave __shfl_up (8 waves),
        // fused cursor advance + counter reset
        unsigned x = 0u, incl = 0u;
        if (t < NBIN) {
            x = cnt[t];
            incl = x;
#pragma unroll
            for (int o = 1; o < 64; o <<= 1) {
                const unsigned y = __shfl_up(incl, (unsigned)o, 64);
                if (lane >= o) incl += y;
            }
            if (lane == 63) wsum[t >> 6] = incl;
        }
        __syncthreads();
        if (t < NBIN) {
            unsigned wo = 0u;
            const int w = t >> 6;
            for (int k = 0; k < w; ++k) wo += wsum[k];
            const unsigned e = wo + incl - x;        // exclusive prefix for bin t
            toff[t] = e;
            ebase[t] = bs2[t] - e;
            bs2[t] += x;
            cnt[t] = 0u;
        }
        __syncthreads();

        // Phase D: place records sorted into LDS
        if (act) {
#pragma unroll
            for (int k = 0; k < 8; ++k) {
                const unsigned bn = (unsigned)(r8[k] >> 55);
                sdata[toff[bn] + sl[k]] = r8[k];
            }
        }
        __syncthreads();

        // Phase E: emission — plain stores; cell-capacity check -> overflow list
        for (int j = t; j < n; j += SCT_THREADS) {
            const unsigned long long u = sdata[j];
            const unsigned sb = (unsigned)(u >> 55);
            const unsigned pos = ebase[sb] + (unsigned)j;
            const unsigned cb = (sb * SCAT_BLOCKS + (unsigned)blockIdx.x) * CAP;
            const unsigned pk = (unsigned)((u >> 26) & 0x1FFFFFFFu);
            const unsigned short vh = (unsigned short)(u & 0xFFFFu);
            if (pos - cb < CAP) {
                recA[pos] = pk;
                recB[pos] = vh;
            } else {
                const unsigned g = atomicAdd(ovf_n, 1u);
                if (g < OVF_CAP) ovf[g] = u;
            }
        }
        __syncthreads();
    }

    // write per-cell counts (capped) for accum: gcnt[blk][bin]
    if (t < NBIN) {
        const unsigned cb = ((unsigned)t * SCAT_BLOCKS + (unsigned)blockIdx.x) * CAP;
        const unsigned total = bs2[t] - cb;
        gcnt[(size_t)blockIdx.x * NBIN + t] = (total < CAP) ? total : CAP;
    }
}

// accumulate one bin from its contiguous [bin][blk] cell region (flat masked scan)
__global__ __launch_bounds__(ACC_THREADS) void k_accum(
        const unsigned* __restrict__ recA, const unsigned short* __restrict__ recB,
        const unsigned* __restrict__ gcnt, const u32x4* __restrict__ sino_b,
        const unsigned long long* __restrict__ ovf, const unsigned* __restrict__ ovf_n,
        float* __restrict__ acc) {
    __shared__ unsigned long long l8[RB_PX * 2];   // 16 KB
    __shared__ unsigned fcnt[SCAT_BLOCKS];         //  1 KB
    const int t = threadIdx.x;
    const int bin = blockIdx.x;
    for (int j = t; j < RB_PX * 2; j += ACC_THREADS) l8[j] = 0ull;
    if (t < SCAT_BLOCKS) fcnt[t] = gcnt[(size_t)t * NBIN + bin];
    __syncthreads();

    const unsigned binbase = (unsigned)bin * CELLS_PER_BIN;
    for (unsigned i = (unsigned)t; i < CELLS_PER_BIN; i += ACC_THREADS) {
        const unsigned frag = i / CAP;             // magic-mul divide by 192
        const unsigned slot = i - frag * CAP;
        const unsigned a = recA[binbase + i];      // coalesced sequential
        const unsigned short hraw = recB[binbase + i];
        if (slot < fcnt[frag]) {
            const float v = __half2float(__ushort_as_half(hraw));
            const int col = (int)(a & 0x7FFFFu);
            const int lr  = (int)(a >> 19);
            fx_accum(lds_off(&l8[(unsigned)lr * 2u]), v, sino_b[col]);
        }
    }

    // fold in rare overflow records for this bin (same fixed-point path)
    {
        unsigned n = *ovf_n;
        if (n > OVF_CAP) n = OVF_CAP;
        for (unsigned i = (unsigned)t; i < n; i += ACC_THREADS) {
            const unsigned long long u = ovf[i];
            if ((unsigned)(u >> 55) != (unsigned)bin) continue;
            const float v = __half2float(__ushort_as_half((unsigned short)(u & 0xFFFFu)));
            const unsigned pk = (unsigned)((u >> 26) & 0x1FFFFFFFu);
            const int col = (int)(pk & 0x7FFFFu);
            const int lr  = (int)(pk >> 19);
            fx_accum(lds_off(&l8[(unsigned)lr * 2u]), v, sino_b[col]);
        }
    }
    lgkm_drain();
    __syncthreads();

    float* dst = acc + (size_t)bin * (RB_PX * 6);
    for (int px = t; px < RB_PX; px += ACC_THREADS) {
        const unsigned long long a0 = l8[px * 2 + 0];
        const unsigned long long a1 = l8[px * 2 + 1];
        const unsigned f2 = (unsigned)(a1 >> 42);         // [n:8 | qden-sum:14]
        const unsigned n = f2 >> 14;
        const float nb = (float)(n * B21);
        float* d = dst + px * 6;
        d[0] = ((float)(int)((unsigned)a0 & M21)         - nb) * FXSI;
        d[1] = ((float)(int)((unsigned)(a0 >> 21) & M21) - nb) * FXSI;
        d[2] = ((float)(int)((unsigned)(a0 >> 42) & M21) - nb) * FXSI;
        d[3] = ((float)(int)((unsigned)a1 & M21)         - nb) * FXSI;
        d[4] = ((float)(int)((unsigned)(a1 >> 21) & M21) - nb) * FXSI;
        d[5] = (float)(f2 & 0x3FFFu) * DENSI;             // sum of vals (positive)
    }
}

// sum 4 shards per pixel, divide, write [BSZ][NPIX]
__global__ void k_reduce(const float* __restrict__ acc, float* __restrict__ out) {
    const int p = blockIdx.x * blockDim.x + threadIdx.x;
    if (p < NPIX) {
        const int rbin = p >> RB_SHIFT, lr = p & (RB_PX - 1);
        float n0 = 0.f, n1 = 0.f, n2 = 0.f, n3 = 0.f, n4 = 0.f, den = 0.f;
#pragma unroll
        for (int s = 0; s < NSHARD; ++s) {
            const float* b = acc + ((size_t)(rbin * NSHARD + s) * RB_PX + lr) * 6;
            n0 += b[0]; n1 += b[1]; n2 += b[2];
            n3 += b[3]; n4 += b[4]; den += b[5];
        }
        const float inv = 1.f / den;
        out[0 * (size_t)NPIX + p] = n0 * inv;
        out[1 * (size_t)NPIX + p] = n1 * inv;
        out[2 * (size_t)NPIX + p] = n2 * inv;
        out[3 * (size_t)NPIX + p] = n3 * inv;
        out[4 * (size_t)NPIX + p] = n4 * inv;
    }
}

// ---------------- fallback kernels (small workspace) ----------------

__global__ void bp_scatter_fb_kernel(const float* __restrict__ sino,
                                     const float* __restrict__ vals,
                                     const int*   __restrict__ rows,
                                     const int*   __restrict__ cols,
                                     float* __restrict__ acc) {
    const long long stride = (long long)gridDim.x * blockDim.x;
    for (long long i = (long long)blockIdx.x * blockDim.x + threadIdx.x;
         i < NNZ; i += stride) {
        const float v = vals[i];
        const int   r = rows[i];
        const int   c = cols[i];
        atomicAdd(acc + (size_t)BSZ * NPIX + r, v);
#pragma unroll
        for (int b = 0; b < BSZ; ++b)
            atomicAdd(acc + (size_t)b * NPIX + r, v * sino[(size_t)b * SINO + c]);
    }
}

__global__ void bp_divide_fb_kernel(const float* __restrict__ acc,
                                    float* __restrict__ out) {
    const int i = blockIdx.x * blockDim.x + threadIdx.x;
    if (i < BSZ * NPIX) {
        const int p = i % NPIX;
        out[i] = acc[i] / acc[(size_t)BSZ * NPIX + p];
    }
}

// ---------------- launch ----------------

extern "C" void kernel_launch(void* const* d_in, const int* in_sizes, int n_in,
                              void* d_out, int out_size, void* d_ws, size_t ws_size,
                              hipStream_t stream) {
    const float* sino = (const float*)d_in[0];
    const float* vals = (const float*)d_in[1];
    const int*   rows = (const int*)d_in[2];
    const int*   cols = (const int*)d_in[3];
    float* out = (float*)d_out;

    // workspace layout (bytes, all 16B-aligned):
    //   recA   : 512 bins * 49152 * 4     = 100,663,296
    //   recB   : 512 bins * 49152 * 2     =  50,331,648
    //   sino_b : SINO * 16                =   8,208,000
    //   acc    : NBIN * RB_PX * 6 * 4     =  12,582,912
    //   gcnt   : SCAT_BLOCKS * NBIN * 4   =     524,288
    //   ovf    : OVF_CAP * 8              =     524,288
    //   ovf_n  : 16
    //   total ~ 172.8 MB
    const size_t recA_b   = (size_t)NBIN * CELLS_PER_BIN * 4;
    const size_t recB_b   = (size_t)NBIN * CELLS_PER_BIN * 2;
    const size_t sino_b_b = (size_t)SINO * 16;
    const size_t acc_b    = (size_t)NBIN * RB_PX * 6 * 4;
    const size_t gcnt_b   = (size_t)SCAT_BLOCKS * NBIN * 4;
    const size_t ovf_b    = (size_t)OVF_CAP * 8;
    const size_t need = recA_b + recB_b + sino_b_b + acc_b + gcnt_b + ovf_b + 16;

    if (ws_size >= need) {
        char* w = (char*)d_ws;
        unsigned*       recA = (unsigned*)w;                w += recA_b;
        unsigned short* recB = (unsigned short*)w;          w += recB_b;
        u32x4*    sinob  = (u32x4*)w;                       w += sino_b_b;
        float*    acc    = (float*)w;                       w += acc_b;
        unsigned* gcnt   = (unsigned*)w;                    w += gcnt_b;
        unsigned long long* ovf = (unsigned long long*)w;   w += ovf_b;
        unsigned* ovf_n  = (unsigned*)w;

        (void)hipMemsetAsync(ovf_n, 0, 4, stream);
        k_scatter<<<SCAT_BLOCKS, SCT_THREADS, 0, stream>>>(
            sino, sinob, vals, rows, cols, recA, recB, gcnt, ovf, ovf_n);
        k_accum<<<NBIN, ACC_THREADS, 0, stream>>>(
            recA, recB, gcnt, sinob, ovf, ovf_n, acc);
        k_reduce<<<(NPIX + 255) / 256, 256, 0, stream>>>(acc, out);
    } else {
        float* acc = (float*)d_ws;
        (void)hipMemsetAsync(acc, 0, (size_t)(BSZ + 1) * NPIX * sizeof(float), stream);
        bp_scatter_fb_kernel<<<2048, 256, 0, stream>>>(sino, vals, rows, cols, acc);
        bp_divide_fb_kernel<<<(BSZ * NPIX + 255) / 256, 256, 0, stream>>>(acc, out);
    }
}